// Round 4
// baseline (318.440 us; speedup 1.0000x reference)
//
#include <hip/hip_runtime.h>

// pred, target: [32,1,1024,1024] f32 -> scalar f32 = mean((softplus(p)-p*t)*w),
// w = 0.1 on 5x5 morphological gradient of binarized target, gated on
// cond = (t.max()==1 && t.min()==0).
//
// R4: oversubscription + MLP. R3 profile showed harness 512MB poison fills
// (~76us @7TB/s) dominate the graph; bits+loss combined ~130us => still
// ~2.2TB/s effective. Fixes:
//   bbl_bits: 2 rows/iter, 8 float4 loads hoisted ahead of ballot clusters.
//   bbl_loss: 256-thr blocks, BAND=16 -> 2048 blocks = 8/CU (was 4/CU at
//             capacity): cross-block overlap hides barrier convoys + VALU.
// Old fused kernel kept as fallback if ws_size < 4 MB + 64 B.

#define IMG     1024
#define BAND    32
#define NBANDS  (IMG / BAND)     // 32 (fallback kernel)
#define BAND2   16
#define NB2     (IMG / BAND2)    // 64 (loss kernel)
#define MAXR2   (BAND2 + 4)      // 20
#define NIMG    32
#define WORDS   16               // 1024 cols / 64 bits
#define WPAD    17               // LDS pad: breaks 4-way bank aliasing
#define HALO    2
#define MAXROWS (BAND + 2 * HALO)
#define NROWS   (NIMG * IMG)     // 32768
#define NTOT    33554432.0

typedef unsigned long long u64;

__device__ __forceinline__ unsigned encf(float f) {
    unsigned u = __float_as_uint(f);
    return (u & 0x80000000u) ? ~u : (u | 0x80000000u);
}
__device__ __forceinline__ float decf(unsigned e) {
    unsigned u = (e & 0x80000000u) ? (e & 0x7fffffffu) : ~e;
    return __uint_as_float(u);
}

__global__ void bbl_init(double* dws, unsigned* uws) {
    if (threadIdx.x == 0) {
        dws[0] = 0.0; dws[1] = 0.0;
        uws[0] = 0xFFFFFFFFu;   // running min (encoded)
        uws[1] = 0u;            // running max (encoded)
    }
}

// ---------------- K1: target -> bit-words + global min/max -------------------
// 2048 blocks x 256 thr = 8192 waves; each wave owns rows {w, w+8192,
// w+16384, w+24576}, processed 2 at a time with 8 float4 loads in flight.
__global__ __launch_bounds__(256) void bbl_bits(
        const float* __restrict__ target,
        u64* __restrict__ bits, unsigned* __restrict__ uws) {
    __shared__ unsigned redMn[4], redMx[4];
    const int tid  = threadIdx.x;
    const int lane = tid & 63;
    const int wv   = tid >> 6;                  // 4 waves/block
    const int waveId = blockIdx.x * 4 + wv;
    const int nWaves = gridDim.x * 4;           // 8192

    float vmin = 3.4e38f, vmax = -3.4e38f;

    for (int row = waveId; row < NROWS; row += 2 * nWaves) {
        const int rowB = row + nWaves;
        const float4* pa = (const float4*)(target + (size_t)row  * IMG);
        const float4* pb = (const float4*)(target + (size_t)rowB * IMG);
        // 8 independent float4 loads in flight
        float4 a0 = pa[lane];       float4 a1 = pa[64 + lane];
        float4 a2 = pa[128 + lane]; float4 a3 = pa[192 + lane];
        float4 b0 = pb[lane];       float4 b1 = pb[64 + lane];
        float4 b2 = pb[128 + lane]; float4 b3 = pb[192 + lane];

        vmin = fminf(vmin, fminf(fminf(a0.x, a0.y), fminf(a0.z, a0.w)));
        vmax = fmaxf(vmax, fmaxf(fmaxf(a0.x, a0.y), fmaxf(a0.z, a0.w)));
        vmin = fminf(vmin, fminf(fminf(a1.x, a1.y), fminf(a1.z, a1.w)));
        vmax = fmaxf(vmax, fmaxf(fmaxf(a1.x, a1.y), fmaxf(a1.z, a1.w)));
        vmin = fminf(vmin, fminf(fminf(a2.x, a2.y), fminf(a2.z, a2.w)));
        vmax = fmaxf(vmax, fmaxf(fmaxf(a2.x, a2.y), fmaxf(a2.z, a2.w)));
        vmin = fminf(vmin, fminf(fminf(a3.x, a3.y), fminf(a3.z, a3.w)));
        vmax = fmaxf(vmax, fmaxf(fmaxf(a3.x, a3.y), fmaxf(a3.z, a3.w)));
        vmin = fminf(vmin, fminf(fminf(b0.x, b0.y), fminf(b0.z, b0.w)));
        vmax = fmaxf(vmax, fmaxf(fmaxf(b0.x, b0.y), fmaxf(b0.z, b0.w)));
        vmin = fminf(vmin, fminf(fminf(b1.x, b1.y), fminf(b1.z, b1.w)));
        vmax = fmaxf(vmax, fmaxf(fmaxf(b1.x, b1.y), fmaxf(b1.z, b1.w)));
        vmin = fminf(vmin, fminf(fminf(b2.x, b2.y), fminf(b2.z, b2.w)));
        vmax = fmaxf(vmax, fmaxf(fmaxf(b2.x, b2.y), fmaxf(b2.z, b2.w)));
        vmin = fminf(vmin, fminf(fminf(b3.x, b3.y), fminf(b3.z, b3.w)));
        vmax = fmaxf(vmax, fmaxf(fmaxf(b3.x, b3.y), fmaxf(b3.z, b3.w)));

        u64 wa = 0ULL, wb = 0ULL;
        #pragma unroll
        for (int it = 0; it < 4; ++it) {
            float4 v = (it == 0) ? a0 : (it == 1) ? a1 : (it == 2) ? a2 : a3;
            u64 c0 = __ballot(v.x > 0.5f);
            u64 c1 = __ballot(v.y > 0.5f);
            u64 c2 = __ballot(v.z > 0.5f);
            u64 c3 = __ballot(v.w > 0.5f);
            if ((lane >> 2) == it) {            // lanes 0..15 pick word = lane
                const int m = lane & 3;
                wa = (m == 0) ? c0 : (m == 1) ? c1 : (m == 2) ? c2 : c3;
            }
        }
        #pragma unroll
        for (int it = 0; it < 4; ++it) {
            float4 v = (it == 0) ? b0 : (it == 1) ? b1 : (it == 2) ? b2 : b3;
            u64 c0 = __ballot(v.x > 0.5f);
            u64 c1 = __ballot(v.y > 0.5f);
            u64 c2 = __ballot(v.z > 0.5f);
            u64 c3 = __ballot(v.w > 0.5f);
            if ((lane >> 2) == it) {
                const int m = lane & 3;
                wb = (m == 0) ? c0 : (m == 1) ? c1 : (m == 2) ? c2 : c3;
            }
        }
        if (lane < 16) {
            bits[(size_t)row  * WORDS + lane] = wa;   // 128 B/row
            bits[(size_t)rowB * WORDS + lane] = wb;
        }
    }

    // min/max reduction: wave shuffles -> LDS -> one atomic pair per block
    for (int off = 32; off > 0; off >>= 1) {
        vmin = fminf(vmin, __shfl_down(vmin, off));
        vmax = fmaxf(vmax, __shfl_down(vmax, off));
    }
    if (lane == 0) { redMn[wv] = encf(vmin); redMx[wv] = encf(vmax); }
    __syncthreads();
    if (tid == 0) {
        unsigned mn = 0xFFFFFFFFu, mx = 0u;
        #pragma unroll
        for (int i = 0; i < 4; ++i) { mn = min(mn, redMn[i]); mx = max(mx, redMx[i]); }
        atomicMin(&uws[0], mn);
        atomicMax(&uws[1], mx);
    }
}

// ---------------- K2: bits -> morphology in LDS; stream pred -> sums ---------
// 2048 blocks x 256 thr (BAND2=16 rows) = 8 blocks/CU: cross-block overlap.
__global__ __launch_bounds__(256) void bbl_loss(
        const float* __restrict__ pred,
        const u64* __restrict__ bits,
        double* __restrict__ dws) {
    __shared__ u64 Bm[MAXR2][WPAD];     // raw bits, interleaved layout
    __shared__ u64 Vd[BAND2][WPAD];     // vertical OR  (dilate, 5 rows)
    __shared__ u64 Ve[BAND2][WPAD];     // vertical AND (erode, 5 rows)
    __shared__ u64 Em[BAND2][WPAD];     // edge bits
    __shared__ float redS1[4], redSe[4];

    const int tid  = threadIdx.x;
    const int lane = tid & 63;
    const int wid  = tid >> 6;           // 4 waves
    const int img  = blockIdx.x / NB2;
    const int r0   = (blockIdx.x % NB2) * BAND2;
    const int hs   = max(r0 - HALO, 0);
    const int he   = min(r0 + BAND2 + HALO, IMG);
    const int nLoaded = he - hs;
    const size_t base = (size_t)img * IMG * IMG;

    // ---- 1a: load bit words for band+halo rows (<= 320 u64 = 2.5 KB)
    {
        const u64* gb = bits + ((size_t)img * IMG + hs) * WORDS;
        for (int i = tid; i < nLoaded * WORDS; i += 256)
            Bm[i >> 4][i & 15] = gb[i];
    }
    __syncthreads();

    // ---- 1b: vertical OR/AND over rows gr-2..gr+2 (clamped; skipped rows are
    //          identity, matching -inf/+inf reduce_window padding)
    {
        const int orow = tid >> 4, w = tid & 15;      // 16*16 = 256 = blockDim
        const int gr = r0 + orow;
        const int lo = max(gr - 2, 0), hi = min(gr + 2, IMG - 1);
        u64 vd = 0ULL, ve = ~0ULL;
        for (int g = lo; g <= hi; ++g) { u64 b = Bm[g - hs][w]; vd |= b; ve &= b; }
        Vd[orow][w] = vd; Ve[orow][w] = ve;
    }
    __syncthreads();

    // ---- 1c: horizontal +-2 in interleaved domain; edge = dilate & ~erode
    {
        const int orow = tid >> 4, w = tid & 15;
        const int k = w & 3;
        u64 hd = Vd[orow][w], he_ = Ve[orow][w];
        #pragma unroll
        for (int dd = 0; dd < 4; ++dd) {
            const int delta = (dd < 2) ? dd - 2 : dd - 1;  // -2,-1,1,2
            const int kp = k + delta;
            u64 td, te;
            if (kp >= 0 && kp <= 3) {               // same 256-block, aligned
                td = Vd[orow][w + delta];
                te = Ve[orow][w + delta];
            } else if (kp > 3) {                    // wraps toward next block
                const int wi = w + delta - 4, wn = w + delta;
                u64 nd = (wn <= 15) ? Vd[orow][wn] : 0ULL;   // OOB col: dilate id
                u64 ne = (wn <= 15) ? Ve[orow][wn] : ~0ULL;  // OOB col: erode id
                td = (Vd[orow][wi] >> 1) | (nd << 63);
                te = (Ve[orow][wi] >> 1) | (ne << 63);
            } else {                                // wraps toward prev block
                const int wi = w + delta + 4, wn = w + delta;
                u64 nd = (wn >= 0) ? Vd[orow][wn] : 0ULL;
                u64 ne = (wn >= 0) ? Ve[orow][wn] : ~0ULL;
                td = (Vd[orow][wi] << 1) | (nd >> 63);
                te = (Ve[orow][wi] << 1) | (ne >> 63);
            }
            hd |= td; he_ &= te;
        }
        Em[orow][w] = hd & ~he_;
    }
    __syncthreads();

    // ---- 2: stream pred float4 (4 hoisted loads/row); bits via LDS broadcast
    float s1 = 0.f, se = 0.f;
    for (int orow = wid * 4; orow < wid * 4 + 4; ++orow) {   // 4 waves x 4 rows
        const int gr = r0 + orow, lr = gr - hs;
        const float4* rowp = (const float4*)(pred + base + (size_t)gr * IMG);
        float4 p0 = rowp[lane];
        float4 p1 = rowp[64 + lane];
        float4 p2 = rowp[128 + lane];
        float4 p3 = rowp[192 + lane];
        #pragma unroll
        for (int it = 0; it < 4; ++it) {
            float4 p = (it == 0) ? p0 : (it == 1) ? p1 : (it == 2) ? p2 : p3;
            u64 e0 = Em[orow][it * 4 + 0], e1 = Em[orow][it * 4 + 1];
            u64 e2 = Em[orow][it * 4 + 2], e3 = Em[orow][it * 4 + 3];
            u64 t0 = Bm[lr][it * 4 + 0],   t1 = Bm[lr][it * 4 + 1];
            u64 t2 = Bm[lr][it * 4 + 2],   t3 = Bm[lr][it * 4 + 3];
            float x, l;
            x = p.x;
            l = fmaxf(x, 0.f) + __logf(1.f + __expf(-fabsf(x)))
                - (((t0 >> lane) & 1ULL) ? x : 0.f);
            s1 += l; se += ((e0 >> lane) & 1ULL) ? l : 0.f;
            x = p.y;
            l = fmaxf(x, 0.f) + __logf(1.f + __expf(-fabsf(x)))
                - (((t1 >> lane) & 1ULL) ? x : 0.f);
            s1 += l; se += ((e1 >> lane) & 1ULL) ? l : 0.f;
            x = p.z;
            l = fmaxf(x, 0.f) + __logf(1.f + __expf(-fabsf(x)))
                - (((t2 >> lane) & 1ULL) ? x : 0.f);
            s1 += l; se += ((e2 >> lane) & 1ULL) ? l : 0.f;
            x = p.w;
            l = fmaxf(x, 0.f) + __logf(1.f + __expf(-fabsf(x)))
                - (((t3 >> lane) & 1ULL) ? x : 0.f);
            s1 += l; se += ((e3 >> lane) & 1ULL) ? l : 0.f;
        }
    }

    // ---- reduce: wave shuffles, 4 waves via LDS, one atomic pair per block
    for (int off = 32; off > 0; off >>= 1) {
        s1 += __shfl_down(s1, off);
        se += __shfl_down(se, off);
    }
    if (lane == 0) { redS1[wid] = s1; redSe[wid] = se; }
    __syncthreads();
    if (tid == 0) {
        float S1 = 0.f, Se = 0.f;
        #pragma unroll
        for (int i = 0; i < 4; ++i) { S1 += redS1[i]; Se += redSe[i]; }
        atomicAdd(&dws[0], (double)S1);
        atomicAdd(&dws[1], (double)Se);
    }
}

// ---------------- fallback: old fused kernel (used if ws too small) ----------
__global__ __launch_bounds__(512) void bbl_main(
        const float* __restrict__ pred,
        const float* __restrict__ target,
        double* __restrict__ dws, unsigned* __restrict__ uws) {
    __shared__ u64 Bm[MAXROWS][WORDS];
    __shared__ u64 Vd[BAND][WORDS];
    __shared__ u64 Ve[BAND][WORDS];
    __shared__ u64 Em[BAND][WORDS];
    __shared__ float    redS1[8], redSe[8];
    __shared__ unsigned redMn[8], redMx[8];

    const int tid  = threadIdx.x;
    const int lane = tid & 63;
    const int wid  = tid >> 6;
    const int img  = blockIdx.x / NBANDS;
    const int r0   = (blockIdx.x % NBANDS) * BAND;
    const int hs   = max(r0 - HALO, 0);
    const int he   = min(r0 + BAND + HALO, IMG);
    const int nLoaded = he - hs;
    const size_t base = (size_t)img * IMG * IMG;

    float vmin = 3.4e38f, vmax = -3.4e38f;

    for (int lr = wid; lr < nLoaded; lr += 8) {
        const float4* rowp = (const float4*)(target + base + (size_t)(hs + lr) * IMG);
        #pragma unroll
        for (int it = 0; it < 4; ++it) {
            float4 v = rowp[it * 64 + lane];
            vmin = fminf(vmin, fminf(fminf(v.x, v.y), fminf(v.z, v.w)));
            vmax = fmaxf(vmax, fmaxf(fmaxf(v.x, v.y), fmaxf(v.z, v.w)));
            u64 b0 = __ballot(v.x > 0.5f);
            u64 b1 = __ballot(v.y > 0.5f);
            u64 b2 = __ballot(v.z > 0.5f);
            u64 b3 = __ballot(v.w > 0.5f);
            if (lane < 4) {
                u64 w = (lane == 0) ? b0 : (lane == 1) ? b1 : (lane == 2) ? b2 : b3;
                Bm[lr][it * 4 + lane] = w;
            }
        }
    }
    __syncthreads();
    {
        const int orow = tid >> 4, w = tid & 15;
        const int gr = r0 + orow;
        const int lo = max(gr - 2, 0), hi = min(gr + 2, IMG - 1);
        u64 vd = 0ULL, ve = ~0ULL;
        for (int g = lo; g <= hi; ++g) { u64 b = Bm[g - hs][w]; vd |= b; ve &= b; }
        Vd[orow][w] = vd; Ve[orow][w] = ve;
    }
    __syncthreads();
    {
        const int orow = tid >> 4, w = tid & 15;
        const int k = w & 3;
        u64 hd = Vd[orow][w], he_ = Ve[orow][w];
        #pragma unroll
        for (int dd = 0; dd < 4; ++dd) {
            const int delta = (dd < 2) ? dd - 2 : dd - 1;
            const int kp = k + delta;
            u64 td, te;
            if (kp >= 0 && kp <= 3) {
                td = Vd[orow][w + delta];
                te = Ve[orow][w + delta];
            } else if (kp > 3) {
                const int wi = w + delta - 4, wn = w + delta;
                u64 nd = (wn <= 15) ? Vd[orow][wn] : 0ULL;
                u64 ne = (wn <= 15) ? Ve[orow][wn] : ~0ULL;
                td = (Vd[orow][wi] >> 1) | (nd << 63);
                te = (Ve[orow][wi] >> 1) | (ne << 63);
            } else {
                const int wi = w + delta + 4, wn = w + delta;
                u64 nd = (wn >= 0) ? Vd[orow][wn] : 0ULL;
                u64 ne = (wn >= 0) ? Ve[orow][wn] : ~0ULL;
                td = (Vd[orow][wi] << 1) | (nd >> 63);
                te = (Ve[orow][wi] << 1) | (ne >> 63);
            }
            hd |= td; he_ &= te;
        }
        Em[orow][w] = hd & ~he_;
    }
    __syncthreads();

    float s1 = 0.f, se = 0.f;
    for (int orow = wid * 4; orow < wid * 4 + 4; ++orow) {
        const int gr = r0 + orow, lr = gr - hs;
        const float4* rowp = (const float4*)(pred + base + (size_t)gr * IMG);
        #pragma unroll
        for (int it = 0; it < 4; ++it) {
            float4 p = rowp[it * 64 + lane];
            u64 e0 = Em[orow][it * 4 + 0], e1 = Em[orow][it * 4 + 1];
            u64 e2 = Em[orow][it * 4 + 2], e3 = Em[orow][it * 4 + 3];
            u64 t0 = Bm[lr][it * 4 + 0],   t1 = Bm[lr][it * 4 + 1];
            u64 t2 = Bm[lr][it * 4 + 2],   t3 = Bm[lr][it * 4 + 3];
            float x, t, loss;
            x = p.x; t = (float)((unsigned)((t0 >> lane) & 1ULL));
            loss = fmaxf(x, 0.f) - x * t + __logf(1.f + __expf(-fabsf(x)));
            s1 += loss; se += ((e0 >> lane) & 1ULL) ? loss : 0.f;
            x = p.y; t = (float)((unsigned)((t1 >> lane) & 1ULL));
            loss = fmaxf(x, 0.f) - x * t + __logf(1.f + __expf(-fabsf(x)));
            s1 += loss; se += ((e1 >> lane) & 1ULL) ? loss : 0.f;
            x = p.z; t = (float)((unsigned)((t2 >> lane) & 1ULL));
            loss = fmaxf(x, 0.f) - x * t + __logf(1.f + __expf(-fabsf(x)));
            s1 += loss; se += ((e2 >> lane) & 1ULL) ? loss : 0.f;
            x = p.w; t = (float)((unsigned)((t3 >> lane) & 1ULL));
            loss = fmaxf(x, 0.f) - x * t + __logf(1.f + __expf(-fabsf(x)));
            s1 += loss; se += ((e3 >> lane) & 1ULL) ? loss : 0.f;
        }
    }

    for (int off = 32; off > 0; off >>= 1) {
        s1   += __shfl_down(s1, off);
        se   += __shfl_down(se, off);
        vmin  = fminf(vmin, __shfl_down(vmin, off));
        vmax  = fmaxf(vmax, __shfl_down(vmax, off));
    }
    if (lane == 0) {
        redS1[wid] = s1; redSe[wid] = se;
        redMn[wid] = encf(vmin); redMx[wid] = encf(vmax);
    }
    __syncthreads();
    if (tid == 0) {
        float S1 = 0.f, Se = 0.f; unsigned mn = 0xFFFFFFFFu, mx = 0u;
        #pragma unroll
        for (int i = 0; i < 8; ++i) {
            S1 += redS1[i]; Se += redSe[i];
            mn = min(mn, redMn[i]); mx = max(mx, redMx[i]);
        }
        atomicAdd(&dws[0], (double)S1);
        atomicAdd(&dws[1], (double)Se);
        atomicMin(&uws[0], mn);
        atomicMax(&uws[1], mx);
    }
}

__global__ void bbl_fin(const double* __restrict__ dws,
                        const unsigned* __restrict__ uws,
                        float* __restrict__ out) {
    if (threadIdx.x == 0) {
        float fmin = decf(uws[0]);
        float fmax = decf(uws[1]);
        bool cond = (fmax == 1.0f) && (fmin == 0.0f);
        double s = cond ? (dws[0] - 0.9 * dws[1]) : dws[0];
        out[0] = (float)(s / NTOT);
    }
}

extern "C" void kernel_launch(void* const* d_in, const int* in_sizes, int n_in,
                              void* d_out, int out_size, void* d_ws, size_t ws_size,
                              hipStream_t stream) {
    const float* pred   = (const float*)d_in[0];
    const float* target = (const float*)d_in[1];
    double*   dws = (double*)d_ws;
    unsigned* uws = (unsigned*)(dws + 2);
    float*    out = (float*)d_out;

    const size_t bits_off   = 64;
    const size_t bits_bytes = (size_t)NROWS * WORDS * sizeof(u64);   // 4 MB

    hipLaunchKernelGGL(bbl_init, dim3(1), dim3(64), 0, stream, dws, uws);
    if (ws_size >= bits_off + bits_bytes) {
        u64* bits = (u64*)((char*)d_ws + bits_off);
        hipLaunchKernelGGL(bbl_bits, dim3(2048), dim3(256), 0, stream,
                           target, bits, uws);
        hipLaunchKernelGGL(bbl_loss, dim3(NIMG * NB2), dim3(256), 0, stream,
                           pred, bits, dws);
    } else {
        hipLaunchKernelGGL(bbl_main, dim3(NIMG * NBANDS), dim3(512), 0, stream,
                           pred, target, dws, uws);
    }
    hipLaunchKernelGGL(bbl_fin, dim3(1), dim3(64), 0, stream, dws, uws, out);
}

// Round 6
// 308.731 us; speedup vs baseline: 1.0315x; 1.0315x over previous
//
#include <hip/hip_runtime.h>

// pred, target: [32,1,1024,1024] f32 -> scalar f32 = mean((softplus(p)-p*t)*w),
// w = 0.1 on 5x5 morphological gradient of binarized target, gated on
// cond = (t.max()==1 && t.min()==0).
//
// R5 resubmit (R5 bench was a GPU-acquisition timeout; kernel never ran).
// Fused single-pass kernel (measured best: 295 vs 308/318 for the split)
// + software-pipelined streaming:
//   phase 1a: depth-1 float4-group pipeline (prefetch g+1 while ballots on g)
//   phase 2:  depth-2 pipeline (prefetch 2 float4 while computing 2), fully
//             unrolled static indexing
//   __launch_bounds__(512,8): cap 64 VGPR, keep 4 blocks/CU (grid = 4/CU).
//   3 launches (init/main/fin).

#define IMG     1024
#define BAND    32
#define NBANDS  (IMG / BAND)     // 32
#define NIMG    32
#define WORDS   16               // 1024 cols / 64 bits
#define HALO    2
#define MAXROWS (BAND + 2 * HALO)
#define NTOT    33554432.0

typedef unsigned long long u64;

__device__ __forceinline__ unsigned encf(float f) {
    unsigned u = __float_as_uint(f);
    return (u & 0x80000000u) ? ~u : (u | 0x80000000u);
}
__device__ __forceinline__ float decf(unsigned e) {
    unsigned u = (e & 0x80000000u) ? (e & 0x7fffffffu) : ~e;
    return __uint_as_float(u);
}

__global__ void bbl_init(double* dws, unsigned* uws) {
    if (threadIdx.x == 0) {
        dws[0] = 0.0; dws[1] = 0.0;
        uws[0] = 0xFFFFFFFFu;   // running min (encoded)
        uws[1] = 0u;            // running max (encoded)
    }
}

__global__ __launch_bounds__(512, 8) void bbl_main(
        const float* __restrict__ pred,
        const float* __restrict__ target,
        double* __restrict__ dws, unsigned* __restrict__ uws) {
    __shared__ u64 Bm[MAXROWS][WORDS];   // raw bits (t>0.5), interleaved layout
    __shared__ u64 Vd[BAND][WORDS];      // vertical OR  (dilate, 5 rows)
    __shared__ u64 Ve[BAND][WORDS];      // vertical AND (erode, 5 rows)
    __shared__ u64 Em[BAND][WORDS];      // edge bits
    __shared__ float    redS1[8], redSe[8];
    __shared__ unsigned redMn[8], redMx[8];

    const int tid  = threadIdx.x;
    const int lane = tid & 63;
    const int wid  = tid >> 6;           // 8 waves
    const int img  = blockIdx.x / NBANDS;
    const int r0   = (blockIdx.x % NBANDS) * BAND;
    const int hs   = max(r0 - HALO, 0);
    const int he   = min(r0 + BAND + HALO, IMG);
    const int nLoaded = he - hs;
    const size_t base = (size_t)img * IMG * IMG;
    const float* tb = target + base;

    float vmin = 3.4e38f, vmax = -3.4e38f;

    // ---- 1a: target stream, depth-1 float4-group pipeline.
    // Wave handles rows lr = wid, wid+8, ... ; 4 float4 groups per row.
    // While ballots run on group g, group g+1's load is in flight.
    {
        int lr = wid, it = 0;
        bool have = (lr < nLoaded);
        float4 cur, nxt;
        if (have)
            cur = ((const float4*)(tb + (size_t)(hs + lr) * IMG))[lane];
        while (have) {
            int nit = it + 1, nlr = lr;
            if (nit == 4) { nit = 0; nlr = lr + 8; }
            const bool nhave = (nlr < nLoaded);
            if (nhave)
                nxt = ((const float4*)(tb + (size_t)(hs + nlr) * IMG))[nit * 64 + lane];
            vmin = fminf(vmin, fminf(fminf(cur.x, cur.y), fminf(cur.z, cur.w)));
            vmax = fmaxf(vmax, fmaxf(fmaxf(cur.x, cur.y), fmaxf(cur.z, cur.w)));
            u64 b0 = __ballot(cur.x > 0.5f);
            u64 b1 = __ballot(cur.y > 0.5f);
            u64 b2 = __ballot(cur.z > 0.5f);
            u64 b3 = __ballot(cur.w > 0.5f);
            if (lane < 4) {
                u64 w = (lane == 0) ? b0 : (lane == 1) ? b1 : (lane == 2) ? b2 : b3;
                Bm[lr][it * 4 + lane] = w;
            }
            cur = nxt; it = nit; lr = nlr; have = nhave;
        }
    }
    __syncthreads();

    // ---- 1b: vertical OR/AND over rows gr-2..gr+2 (clamped; skipped rows are
    //          identity, matching -inf/+inf reduce_window padding)
    {
        const int orow = tid >> 4, w = tid & 15;      // 32*16 = 512 = blockDim
        const int gr = r0 + orow;
        const int lo = max(gr - 2, 0), hi = min(gr + 2, IMG - 1);
        u64 vd = 0ULL, ve = ~0ULL;
        for (int g = lo; g <= hi; ++g) { u64 b = Bm[g - hs][w]; vd |= b; ve &= b; }
        Vd[orow][w] = vd; Ve[orow][w] = ve;
    }
    __syncthreads();

    // ---- 1c: horizontal +-2 in interleaved domain; edge = dilate & ~erode
    {
        const int orow = tid >> 4, w = tid & 15;
        const int k = w & 3;
        u64 hd = Vd[orow][w], he_ = Ve[orow][w];
        #pragma unroll
        for (int dd = 0; dd < 4; ++dd) {
            const int delta = (dd < 2) ? dd - 2 : dd - 1;  // -2,-1,1,2
            const int kp = k + delta;
            u64 td, te;
            if (kp >= 0 && kp <= 3) {               // same 256-block, aligned
                td = Vd[orow][w + delta];
                te = Ve[orow][w + delta];
            } else if (kp > 3) {                    // wraps toward next block
                const int wi = w + delta - 4, wn = w + delta;
                u64 nd = (wn <= 15) ? Vd[orow][wn] : 0ULL;   // OOB col: dilate id
                u64 ne = (wn <= 15) ? Ve[orow][wn] : ~0ULL;  // OOB col: erode id
                td = (Vd[orow][wi] >> 1) | (nd << 63);
                te = (Ve[orow][wi] >> 1) | (ne << 63);
            } else {                                // wraps toward prev block
                const int wi = w + delta + 4, wn = w + delta;
                u64 nd = (wn >= 0) ? Vd[orow][wn] : 0ULL;
                u64 ne = (wn >= 0) ? Ve[orow][wn] : ~0ULL;
                td = (Vd[orow][wi] << 1) | (nd >> 63);
                te = (Ve[orow][wi] << 1) | (ne >> 63);
            }
            hd |= td; he_ &= te;
        }
        Em[orow][w] = hd & ~he_;
    }
    __syncthreads();

    // ---- 2: pred stream, depth-2 pipeline. Wave owns rows rw..rw+3;
    // 16 float4 groups flattened; while computing groups (j,j+1), loads for
    // (j+2,j+3) are in flight. All indices static after unroll.
    float s1 = 0.f, se = 0.f;
    {
        const int rw = wid * 4;
        const float* pb = pred + base;
        float4 A0, A1, B0, B1;
        {
            const float4* rp = (const float4*)(pb + (size_t)(r0 + rw) * IMG);
            A0 = rp[lane]; A1 = rp[64 + lane];
        }
        #pragma unroll
        for (int j = 0; j < 16; j += 2) {
            if (j + 2 < 16) {
                const int j2 = j + 2, j3 = j + 3;
                const float4* rp2 = (const float4*)(pb + (size_t)(r0 + rw + (j2 >> 2)) * IMG);
                const float4* rp3 = (const float4*)(pb + (size_t)(r0 + rw + (j3 >> 2)) * IMG);
                B0 = rp2[(j2 & 3) * 64 + lane];
                B1 = rp3[(j3 & 3) * 64 + lane];
            }
            #pragma unroll
            for (int q = 0; q < 2; ++q) {
                const int jj   = j + q;
                const int orow = rw + (jj >> 2);
                const int itp  = jj & 3;
                const int lrp  = r0 + orow - hs;
                const float4 p = q ? A1 : A0;
                u64 e0 = Em[orow][itp * 4 + 0], e1 = Em[orow][itp * 4 + 1];
                u64 e2 = Em[orow][itp * 4 + 2], e3 = Em[orow][itp * 4 + 3];
                u64 t0 = Bm[lrp][itp * 4 + 0],  t1 = Bm[lrp][itp * 4 + 1];
                u64 t2 = Bm[lrp][itp * 4 + 2],  t3 = Bm[lrp][itp * 4 + 3];
                float x, t, loss;
                x = p.x; t = (float)((unsigned)((t0 >> lane) & 1ULL));
                loss = fmaxf(x, 0.f) - x * t + __logf(1.f + __expf(-fabsf(x)));
                s1 += loss; se += ((e0 >> lane) & 1ULL) ? loss : 0.f;
                x = p.y; t = (float)((unsigned)((t1 >> lane) & 1ULL));
                loss = fmaxf(x, 0.f) - x * t + __logf(1.f + __expf(-fabsf(x)));
                s1 += loss; se += ((e1 >> lane) & 1ULL) ? loss : 0.f;
                x = p.z; t = (float)((unsigned)((t2 >> lane) & 1ULL));
                loss = fmaxf(x, 0.f) - x * t + __logf(1.f + __expf(-fabsf(x)));
                s1 += loss; se += ((e2 >> lane) & 1ULL) ? loss : 0.f;
                x = p.w; t = (float)((unsigned)((t3 >> lane) & 1ULL));
                loss = fmaxf(x, 0.f) - x * t + __logf(1.f + __expf(-fabsf(x)));
                s1 += loss; se += ((e3 >> lane) & 1ULL) ? loss : 0.f;
            }
            A0 = B0; A1 = B1;
        }
    }

    // ---- reduce: wave shuffles, 8 waves via LDS, one atomic set per block
    for (int off = 32; off > 0; off >>= 1) {
        s1   += __shfl_down(s1, off);
        se   += __shfl_down(se, off);
        vmin  = fminf(vmin, __shfl_down(vmin, off));
        vmax  = fmaxf(vmax, __shfl_down(vmax, off));
    }
    if (lane == 0) {
        redS1[wid] = s1; redSe[wid] = se;
        redMn[wid] = encf(vmin); redMx[wid] = encf(vmax);
    }
    __syncthreads();
    if (tid == 0) {
        float S1 = 0.f, Se = 0.f; unsigned mn = 0xFFFFFFFFu, mx = 0u;
        #pragma unroll
        for (int i = 0; i < 8; ++i) {
            S1 += redS1[i]; Se += redSe[i];
            mn = min(mn, redMn[i]); mx = max(mx, redMx[i]);
        }
        atomicAdd(&dws[0], (double)S1);
        atomicAdd(&dws[1], (double)Se);
        atomicMin(&uws[0], mn);
        atomicMax(&uws[1], mx);
    }
}

__global__ void bbl_fin(const double* __restrict__ dws,
                        const unsigned* __restrict__ uws,
                        float* __restrict__ out) {
    if (threadIdx.x == 0) {
        float fmin = decf(uws[0]);
        float fmax = decf(uws[1]);
        bool cond = (fmax == 1.0f) && (fmin == 0.0f);
        double s = cond ? (dws[0] - 0.9 * dws[1]) : dws[0];
        out[0] = (float)(s / NTOT);
    }
}

extern "C" void kernel_launch(void* const* d_in, const int* in_sizes, int n_in,
                              void* d_out, int out_size, void* d_ws, size_t ws_size,
                              hipStream_t stream) {
    const float* pred   = (const float*)d_in[0];
    const float* target = (const float*)d_in[1];
    double*   dws = (double*)d_ws;
    unsigned* uws = (unsigned*)(dws + 2);
    float*    out = (float*)d_out;

    hipLaunchKernelGGL(bbl_init, dim3(1), dim3(64), 0, stream, dws, uws);
    hipLaunchKernelGGL(bbl_main, dim3(NIMG * NBANDS), dim3(512), 0, stream,
                       pred, target, dws, uws);
    hipLaunchKernelGGL(bbl_fin, dim3(1), dim3(64), 0, stream, dws, uws, out);
}